// Round 16
// baseline (1645.605 us; speedup 1.0000x reference)
//
#include <hip/hip_runtime.h>
#include <hip/hip_bf16.h>

typedef __attribute__((ext_vector_type(8))) short s16x8;
typedef __attribute__((ext_vector_type(4))) short s16x4;
typedef __attribute__((ext_vector_type(4))) float f32x4;
typedef __hip_bfloat16 bf16;

__device__ __forceinline__ f32x4 mfma16(s16x8 a, s16x8 b, f32x4 c){
  return __builtin_amdgcn_mfma_f32_16x16x32_bf16(a, b, c, 0, 0, 0);
}
__device__ __forceinline__ float geluf(float x){
  return 0.5f * x * (1.f + erff(x * 0.70710678118654752f));
}
__device__ __forceinline__ void gload16(const bf16* g, void* l){
  __builtin_amdgcn_global_load_lds(
      (const __attribute__((address_space(1))) unsigned int*)(g),
      (__attribute__((address_space(3))) unsigned int*)(l), 16, 0, 0);
}

// ---------------- weight prep ----------------
__global__ __launch_bounds__(256) void k_transpose_cast(const float* __restrict__ in,
                                                        bf16* __restrict__ out, int K, int N){
  __shared__ float t[32][33];
  int n0 = blockIdx.x * 32, k0 = blockIdx.y * 32;
  int tx = threadIdx.x & 31, ty = threadIdx.x >> 5;
  #pragma unroll
  for (int j = 0; j < 4; ++j) t[ty + j*8][tx] = in[(size_t)(k0 + ty + j*8) * N + n0 + tx];
  __syncthreads();
  #pragma unroll
  for (int j = 0; j < 4; ++j) out[(size_t)(n0 + ty + j*8) * K + k0 + tx] = __float2bfloat16(t[tx][ty + j*8]);
}

__global__ __launch_bounds__(256) void k_cast(const float* __restrict__ in, bf16* __restrict__ out, int n){
  int i = blockIdx.x * 256 + threadIdx.x;
  if (i < n) out[i] = __float2bfloat16(in[i]);
}

// conv2_w [384][384][3][3] -> [cout][dy][dx*384+ci]  (ldb = 3456)
__global__ __launch_bounds__(256) void k_permute_conv2(const float* __restrict__ in, bf16* __restrict__ out){
  int i = blockIdx.x * 256 + threadIdx.x;   // 1327104 total
  int co = i / 3456;
  int r = i - co * 3456;
  int dy = r / 1152;
  int r2 = r - dy * 1152;
  int dx = r2 / 384;
  int ci = r2 - dx * 384;
  out[i] = __float2bfloat16(in[(size_t)((co * 384 + ci) * 3 + dy) * 3 + dx]);
}

// zero-fill bf16 buffer, n8 = elements/8
__global__ __launch_bounds__(256) void k_zero(bf16* __restrict__ p, int n8){
  int i = blockIdx.x * 256 + threadIdx.x;
  if (i < n8){
    s16x8 z = {0,0,0,0,0,0,0,0};
    *(s16x8*)(p + (size_t)i * 8) = z;
  }
}

// bf16 copy, n8 = elements/8
__global__ __launch_bounds__(256) void k_copy(const bf16* __restrict__ in, bf16* __restrict__ out, int n8){
  int i = blockIdx.x * 256 + threadIdx.x;
  if (i < n8){
    s16x8 v = *(const s16x8*)(in + (size_t)i * 8);
    *(s16x8*)(out + (size_t)i * 8) = v;
  }
}

// onehot table: oneh[j][32], j in [0,224): oneh[j][j/14] = 1, oneh[j][16 + j%14] = 1 (j<196)
__global__ __launch_bounds__(256) void k_onehot(bf16* __restrict__ oneh){
  for (int idx = threadIdx.x; idx < 7168; idx += 256){
    int j = idx >> 5, kk = idx & 31;
    float v = 0.f;
    if (j < 196){
      if (kk == j / 14) v = 1.f;
      if (kk == 16 + (j - (j / 14) * 14)) v = 1.f;
    }
    oneh[idx] = __float2bfloat16(v);
  }
}

// pad K/V rows from qkv bias: padkv[0:768) = 0.125*qkv_b[768+i]; padkv[768:1536) = qkv_b[1536+i]
__global__ __launch_bounds__(256) void k_padkv(const float* __restrict__ qkv_b, bf16* __restrict__ padkv){
  int i = blockIdx.x * 256 + threadIdx.x;
  if (i < 1536){
    float v = (i < 768) ? qkv_b[768 + i] * 0.125f : qkv_b[1536 + (i - 768)];
    padkv[i] = __float2bfloat16(v);
  }
}

// ---------------- row LayerNorm (768 wide, eps 1e-5) -> bf16 ----------------
template<typename Tin>
__global__ __launch_bounds__(256) void k_lnrow(const Tin* __restrict__ xin, const float* __restrict__ w,
                                               const float* __restrict__ b, bf16* __restrict__ out){
  int row = blockIdx.x * 4 + (threadIdx.x >> 6);
  int lane = threadIdx.x & 63;
  const Tin* src = xin + (size_t)row * 768;
  bf16* dst = out + (size_t)row * 768;
  float v[12]; float s = 0.f, sq = 0.f;
  #pragma unroll
  for (int p = 0; p < 3; ++p){
    int c0 = lane * 4 + p * 256;
    if constexpr (sizeof(Tin) == 4){
      f32x4 t = *(const f32x4*)(src + c0);
      #pragma unroll
      for (int e = 0; e < 4; ++e) v[p*4+e] = t[e];
    } else {
      s16x4 t = *(const s16x4*)(src + c0);
      #pragma unroll
      for (int e = 0; e < 4; ++e) v[p*4+e] = __bfloat162float(__builtin_bit_cast(bf16, (unsigned short)t[e]));
    }
    #pragma unroll
    for (int e = 0; e < 4; ++e){ s += v[p*4+e]; sq += v[p*4+e] * v[p*4+e]; }
  }
  #pragma unroll
  for (int o = 1; o < 64; o <<= 1){ s += __shfl_xor(s, o); sq += __shfl_xor(sq, o); }
  float mean = s * (1.f / 768.f);
  float rstd = rsqrtf(sq * (1.f / 768.f) - mean * mean + 1e-5f);
  #pragma unroll
  for (int p = 0; p < 3; ++p){
    int c0 = lane * 4 + p * 256;
    s16x4 o4;
    #pragma unroll
    for (int e = 0; e < 4; ++e){
      bf16 h = __float2bfloat16((v[p*4+e] - mean) * rstd * w[c0 + e] + b[c0 + e]);
      o4[e] = (short)__builtin_bit_cast(unsigned short, h);
    }
    *(s16x4*)(dst + c0) = o4;
  }
}

// channel-first LN (eps 1e-6) + GELU over C=384; PAD: write into [8][66][66][384] interior
template<typename Tin, bool PAD>
__global__ __launch_bounds__(256) void k_lncf_gelu(const Tin* __restrict__ in, const float* __restrict__ w,
                                                   const float* __restrict__ b, bf16* __restrict__ out){
  int row = blockIdx.x * 4 + (threadIdx.x >> 6);
  int lane = threadIdx.x & 63;
  const Tin* src = in + (size_t)row * 384;
  bf16* dst;
  if constexpr (PAD){
    int bb = row >> 12, y = (row >> 6) & 63, xx = row & 63;
    dst = out + (size_t)((bb * 66 + y + 1) * 66 + (xx + 1)) * 384;
  } else {
    dst = out + (size_t)row * 384;
  }
  float buf[6]; float s = 0.f, sq = 0.f;
  #pragma unroll
  for (int p = 0; p < 6; ++p){
    float v;
    if constexpr (sizeof(Tin) == 4) v = src[lane + p * 64];
    else v = __bfloat162float(src[lane + p * 64]);
    buf[p] = v; s += v; sq += v * v;
  }
  #pragma unroll
  for (int o = 1; o < 64; o <<= 1){ s += __shfl_xor(s, o); sq += __shfl_xor(sq, o); }
  float mean = s * (1.f / 384.f);
  float rstd = rsqrtf(sq * (1.f / 384.f) - mean * mean + 1e-6f);
  #pragma unroll
  for (int p = 0; p < 6; ++p){
    int c = lane + p * 64;
    dst[c] = __float2bfloat16(geluf((buf[p] - mean) * rstd * w[c] + b[c]));
  }
}

// final: outp[row] = fp32(res[row]) + LN_cf(c3[row]); nrows rows
__global__ __launch_bounds__(256) void k_final(const bf16* __restrict__ c3, const float* __restrict__ w,
                                               const float* __restrict__ b, const bf16* __restrict__ res,
                                               float* __restrict__ outp, int nrows){
  int row = blockIdx.x * 4 + (threadIdx.x >> 6);
  if (row >= nrows) return;
  int lane = threadIdx.x & 63;
  const bf16* src = c3 + (size_t)row * 768;
  const bf16* rsp = res + (size_t)row * 768;
  float* dst = outp + (size_t)row * 768;
  float buf[12]; float s = 0.f, sq = 0.f;
  #pragma unroll
  for (int p = 0; p < 12; ++p){
    float v = __bfloat162float(src[lane + p * 64]);
    buf[p] = v; s += v; sq += v * v;
  }
  #pragma unroll
  for (int o = 1; o < 64; o <<= 1){ s += __shfl_xor(s, o); sq += __shfl_xor(sq, o); }
  float mean = s * (1.f / 768.f);
  float rstd = rsqrtf(sq * (1.f / 768.f) - mean * mean + 1e-6f);
  #pragma unroll
  for (int p = 0; p < 12; ++p){
    int c = lane + p * 64;
    dst[c] = __bfloat162float(rsp[c]) + (buf[p] - mean) * rstd * w[c] + b[c];
  }
}

// ---------------- rel-pos tables via MFMA (Q from token-major qkvb chunk) ----------------
__global__ __launch_bounds__(256) void k_relm(const bf16* __restrict__ qkvb, const bf16* __restrict__ rphb,
                                              const bf16* __restrict__ rpwb, bf16* __restrict__ relc){
  const int lane = threadIdx.x & 63, wv = threadIdx.x >> 6;
  const int col16 = lane & 15, kgrp = lane >> 4;
  const int w = blockIdx.x * 4 + wv;            // 8400 waves per chunk
  const int wh = w / 14, r = w - (w / 14) * 14; // wh 0..599 chunk-local
  const int wdwL = wh / 12, hd = wh - wdwL * 12;
  const int bloc = wdwL / 25;
  const int wrm = wdwL - bloc * 25;
  const int wy = wrm / 5, wx = wrm - (wrm / 5) * 5;
  const int qrow = r * 14 + col16;
  const int qq = qrow > 195 ? 195 : qrow;
  int qy = wy * 14 + qq / 14, qx = wx * 14 + qq - (qq / 14) * 14;
  if (qy > 63) qy = 63;
  if (qx > 63) qx = 63;
  const bf16* qa = qkvb + (size_t)(bloc * 4096 + qy * 64 + qx) * 2304 + hd * 64 + kgrp * 8;
  s16x8 a0 = *(const s16x8*)qa;
  s16x8 a1 = *(const s16x8*)(qa + 32);
  #pragma unroll
  for (int t = 0; t < 2; ++t){
    const bf16* bh = rphb + (t * 16 + col16) * 64 + kgrp * 8;
    const bf16* bw = rpwb + (t * 16 + col16) * 64 + kgrp * 8;
    f32x4 zh = {0.f,0.f,0.f,0.f}, zw = zh;
    zh = mfma16(a0, *(const s16x8*)bh, zh);
    zh = mfma16(a1, *(const s16x8*)(bh + 32), zh);
    zw = mfma16(a0, *(const s16x8*)bw, zw);
    zw = mfma16(a1, *(const s16x8*)(bw + 32), zw);
    #pragma unroll
    for (int e = 0; e < 4; ++e){
      int m = kgrp * 4 + e;
      if (m < 14){
        int q = r * 14 + m;
        int j = t * 16 + col16;
        size_t base = ((size_t)wh * 196 + q) * 32;
        int kk = r + 13 - j;
        if (kk >= 0 && kk <= 13) relc[base + kk] = __float2bfloat16(zh[e]);
        int kkw = m + 13 - j;
        if (kkw >= 0 && kkw <= 13) relc[base + 16 + kkw] = __float2bfloat16(zw[e]);
      }
    }
  }
}

// ---------------- attention (chunk of 50 windows x 12 heads = 600 blocks) ----------------
__global__ __launch_bounds__(256) void k_attn(const bf16* __restrict__ qkvb,
                                              const bf16* __restrict__ relc,
                                              const bf16* __restrict__ oneh,
                                              const bf16* __restrict__ padkv,
                                              bf16* __restrict__ out, int wdw_base){
  __shared__ __align__(16) bf16 Vt[64][236];
  __shared__ __align__(16) bf16 Pst[4][16][236];
  const int tid = threadIdx.x;
  const int lane = tid & 63, wv = tid >> 6;
  const int col16 = lane & 15, kgrp = lane >> 4;
  const int bxl = blockIdx.x;
  const int wdwL = bxl / 12, hd = bxl - wdwL * 12;
  const int wdw = wdw_base + wdwL;
  const int bb = wdw / 25, wr = wdw - bb * 25;
  const int wy = wr / 5, wx = wr - (wr / 5) * 5;
  const int bloc = wdwL / 25;
  const bf16* rc = relc + (size_t)bxl * 196 * 32;
  const bf16* padK = padkv;
  const bf16* padV = padkv + 768;

  for (int i = tid; i < 3584; i += 256){
    int tok = i >> 4;
    int d0 = (i & 15) * 4;
    if (tok < 196){
      int y = wy * 14 + tok / 14, xx = wx * 14 + tok - (tok / 14) * 14;
      const bf16* src;
      if (y < 64 && xx < 64)
        src = qkvb + (size_t)(bloc * 4096 + y * 64 + xx) * 2304 + 1536 + hd * 64 + d0;
      else
        src = padV + hd * 64 + d0;
      s16x4 vv = *(const s16x4*)src;
      Vt[d0][tok]   = __builtin_bit_cast(bf16, (unsigned short)vv[0]);
      Vt[d0+1][tok] = __builtin_bit_cast(bf16, (unsigned short)vv[1]);
      Vt[d0+2][tok] = __builtin_bit_cast(bf16, (unsigned short)vv[2]);
      Vt[d0+3][tok] = __builtin_bit_cast(bf16, (unsigned short)vv[3]);
    } else {
      bf16 z = __float2bfloat16(0.f);
      Vt[d0][tok] = z; Vt[d0+1][tok] = z; Vt[d0+2][tok] = z; Vt[d0+3][tok] = z;
    }
  }
  __syncthreads();

  for (int band = wv; band < 14; band += 4){
    const int qrow = band * 16 + col16;
    const int qq = qrow < 196 ? qrow : 195;
    int qy = wy * 14 + qq / 14, qx = wx * 14 + qq - (qq / 14) * 14;
    if (qy > 63) qy = 63;
    if (qx > 63) qx = 63;
    const bf16* qa = qkvb + (size_t)(bloc * 4096 + qy * 64 + qx) * 2304 + hd * 64 + kgrp * 8;
    s16x8 a0 = *(const s16x8*)(qa);
    s16x8 a1 = *(const s16x8*)(qa + 32);
    s16x8 a2 = *(const s16x8*)(rc + (size_t)qq * 32 + kgrp * 8);
    f32x4 s[14];
    #pragma unroll
    for (int t = 0; t < 14; ++t){
      int j = t * 16 + col16;
      int jc = j < 196 ? j : 195;
      int ky = wy * 14 + jc / 14, kx = wx * 14 + jc - (jc / 14) * 14;
      const bf16* kb;
      if (ky < 64 && kx < 64)
        kb = qkvb + (size_t)(bloc * 4096 + ky * 64 + kx) * 2304 + 768 + hd * 64 + kgrp * 8;
      else
        kb = padK + hd * 64 + kgrp * 8;
      s16x8 oh = *(const s16x8*)(oneh + (size_t)j * 32 + kgrp * 8);
      f32x4 z = {0.f, 0.f, 0.f, 0.f};
      z = mfma16(a0, *(const s16x8*)kb, z);
      z = mfma16(a1, *(const s16x8*)(kb + 32), z);
      z = mfma16(a2, oh, z);
      s[t] = z;
    }
    float mx[4] = {-1e30f, -1e30f, -1e30f, -1e30f};
    #pragma unroll
    for (int t = 0; t < 14; ++t){
      bool valid = (t * 16 + col16) < 196;
      #pragma unroll
      for (int r = 0; r < 4; ++r){
        float v = valid ? s[t][r] : -1e30f;
        s[t][r] = v;
        mx[r] = fmaxf(mx[r], v);
      }
    }
    #pragma unroll
    for (int r = 0; r < 4; ++r)
      #pragma unroll
      for (int o = 1; o < 16; o <<= 1) mx[r] = fmaxf(mx[r], __shfl_xor(mx[r], o));
    float sm[4] = {0.f, 0.f, 0.f, 0.f};
    #pragma unroll
    for (int t = 0; t < 14; ++t)
      #pragma unroll
      for (int r = 0; r < 4; ++r){
        float p = __expf(s[t][r] - mx[r]);
        s[t][r] = p; sm[r] += p;
      }
    #pragma unroll
    for (int r = 0; r < 4; ++r){
      #pragma unroll
      for (int o = 1; o < 16; o <<= 1) sm[r] += __shfl_xor(sm[r], o);
      sm[r] = 1.f / sm[r];
    }
    #pragma unroll
    for (int t = 0; t < 14; ++t)
      #pragma unroll
      for (int r = 0; r < 4; ++r)
        Pst[wv][kgrp * 4 + r][t * 16 + col16] = __float2bfloat16(s[t][r] * sm[r]);
    f32x4 o0 = {0.f,0.f,0.f,0.f}, o1 = o0, o2 = o0, o3 = o0;
    #pragma unroll
    for (int ks = 0; ks < 7; ++ks){
      s16x8 pa = *(const s16x8*)&Pst[wv][col16][ks * 32 + kgrp * 8];
      s16x8 v0 = *(const s16x8*)&Vt[col16][ks * 32 + kgrp * 8];
      s16x8 v1 = *(const s16x8*)&Vt[16 + col16][ks * 32 + kgrp * 8];
      s16x8 v2 = *(const s16x8*)&Vt[32 + col16][ks * 32 + kgrp * 8];
      s16x8 v3 = *(const s16x8*)&Vt[48 + col16][ks * 32 + kgrp * 8];
      o0 = mfma16(pa, v0, o0); o1 = mfma16(pa, v1, o1);
      o2 = mfma16(pa, v2, o2); o3 = mfma16(pa, v3, o3);
    }
    f32x4 oo[4] = {o0, o1, o2, o3};
    #pragma unroll
    for (int nt = 0; nt < 4; ++nt)
      #pragma unroll
      for (int r = 0; r < 4; ++r){
        int q = band * 16 + kgrp * 4 + r;
        if (q < 196){
          int y = wy * 14 + q / 14, xx = wx * 14 + (q - (q / 14) * 14);
          if (y < 64 && xx < 64){
            size_t tokidx = (size_t)((bb * 64 + y) * 64 + xx);
            out[tokidx * 768 + hd * 64 + nt * 16 + col16] = __float2bfloat16(oo[nt][r]);
          }
        }
      }
  }
}

// ---------------- 256x256 8-wave MFMA GEMM (BK=64, 128KiB LDS dbuf, counted vmcnt) ----------------
// MODE 2: gelu(v + bias)   MODE 5: qkv (+bias, 0.125 on cols [768,1536))
template<int MODE>
__global__ __launch_bounds__(512, 2) void k_gemm256(
    const bf16* __restrict__ A, const bf16* __restrict__ BT,
    const float* __restrict__ bias, bf16* __restrict__ outB,
    int K, int lda, int ldb, int N)
{
  __shared__ __align__(16) bf16 SH[65536];   // As[2][16384] | Bs[2][16384]; reused as 256x256 C-tile
  const int tid = threadIdx.x;
  const int lane = tid & 63;
  const int wid = tid >> 6;
  const int wm = wid >> 2, wn = wid & 3;
  const int col16 = lane & 15, kgrp = lane >> 4;
  const int cpx = gridDim.x >> 3;
  const int bxs = ((int)blockIdx.x & 7) * cpx + ((int)blockIdx.x >> 3);
  const int m0 = bxs * 256;
  const int n0 = blockIdx.y * 256;

  // staging: thread covers rows (tid>>3)+64i, chunk slot tid&7; LDS(row,c)=global(row, c^(row&7))
  const int srow = tid >> 3;
  const int cslot = tid & 7;
  const int cs = (cslot ^ (srow & 7)) * 8;
  const bf16* ap[4];
  const bf16* bp[4];
  #pragma unroll
  for (int i = 0; i < 4; ++i){
    ap[i] = A  + (size_t)(m0 + srow + 64 * i) * lda + cs;
    bp[i] = BT + (size_t)(n0 + srow + 64 * i) * ldb + cs;
  }

  auto stage = [&](int bufi, int t){
    char* ab = (char*)(SH + bufi * 16384);
    char* bb = (char*)(SH + 32768 + bufi * 16384);
    #pragma unroll
    for (int i = 0; i < 4; ++i)
      gload16(ap[i] + t * 64, ab + i * 8192 + tid * 16);
    #pragma unroll
    for (int i = 0; i < 4; ++i)
      gload16(bp[i] + t * 64, bb + i * 8192 + tid * 16);
  };

  f32x4 acc[8][4];
  f32x4 z4 = {0.f,0.f,0.f,0.f};
  #pragma unroll
  for (int mi = 0; mi < 8; ++mi)
    #pragma unroll
    for (int ni = 0; ni < 4; ++ni) acc[mi][ni] = z4;

  const int nt = K >> 6;   // >= 2 at all call sites (K=768 -> 12)
  stage(0, 0);
  stage(1, 1);
  for (int s = 0; s < nt; ++s){
    if (s + 1 < nt) asm volatile("s_waitcnt vmcnt(8)" ::: "memory");  // drain tile s; tile s+1 in flight
    else            asm volatile("s_waitcnt vmcnt(0)" ::: "memory");
    __builtin_amdgcn_s_barrier();
    __builtin_amdgcn_sched_barrier(0);
    const bf16* ab = SH + (s & 1) * 16384;
    const bf16* bb = SH + 32768 + (s & 1) * 16384;
    s16x8 bfv[4][2];
    #pragma unroll
    for (int ni = 0; ni < 4; ++ni)
      #pragma unroll
      for (int ks = 0; ks < 2; ++ks){
        int row = wn * 64 + ni * 16 + col16;
        bfv[ni][ks] = *(const s16x8*)(bb + row * 64 + ((ks * 4 + kgrp) ^ (row & 7)) * 8);
      }
    #pragma unroll
    for (int mi = 0; mi < 8; ++mi){
      int row = wm * 128 + mi * 16 + col16;
      s16x8 a0 = *(const s16x8*)(ab + row * 64 + ((kgrp) ^ (row & 7)) * 8);
      s16x8 a1 = *(const s16x8*)(ab + row * 64 + ((4 + kgrp) ^ (row & 7)) * 8);
      #pragma unroll
      for (int ni = 0; ni < 4; ++ni){
        acc[mi][ni] = mfma16(a0, bfv[ni][0], acc[mi][ni]);
        acc[mi][ni] = mfma16(a1, bfv[ni][1], acc[mi][ni]);
      }
    }
    __builtin_amdgcn_sched_barrier(0);
    __builtin_amdgcn_s_barrier();       // all waves done reading buf (s&1)
    if (s + 2 < nt) stage(s & 1, s + 2);
  }

  // epilogue: C tile -> LDS (swizzled), then coalesced copy-out
  #pragma unroll
  for (int mi = 0; mi < 8; ++mi){
    #pragma unroll
    for (int ni = 0; ni < 4; ++ni){
      #pragma unroll
      for (int e = 0; e < 4; ++e){
        int r = wm * 128 + mi * 16 + kgrp * 4 + e;
        int c = wn * 64 + ni * 16 + col16;
        float v = acc[mi][ni][e];
        float t;
        if constexpr (MODE == 2){
          t = geluf(v + bias[n0 + c]);
        } else {
          int col = n0 + c;
          t = (v + bias[col]) * ((col >= 768 && col < 1536) ? 0.125f : 1.f);
        }
        SH[r * 256 + (c ^ (((r >> 2) & 7) << 3))] = __float2bfloat16(t);
      }
    }
  }
  __syncthreads();
  #pragma unroll
  for (int it = 0; it < 16; ++it){
    int cid = it * 512 + tid;
    int r = cid >> 5, ch = cid & 31;
    int sch = ch ^ ((r >> 2) & 7);
    s16x8 val = *(s16x8*)&SH[r * 256 + sch * 8];
    *(s16x8*)(outB + (size_t)(m0 + r) * N + n0 + ch * 8) = val;
  }
}

// ---------------- LDS-staged MFMA GEMM (128x128, 4 waves, chunk-XOR swizzle, XCD swizzle) ----------------
// Coalesced epilogue via LDS C-tile restage; residual added at copy-out.
// MODE 1: + bias + Af(fp32)   MODE 2: gelu(+bias)   MODE 3: + bias + Rb(bf16)   MODE 4: plain
// STG 0: linear rows  STG 2: conv2 padded dy-shift
template<int MODE, int STG>
__global__ __launch_bounds__(256) void k_gemm(
    const bf16* __restrict__ A, const bf16* __restrict__ BT,
    const float* __restrict__ bias, const float* __restrict__ Af,
    const bf16* __restrict__ Rb, bf16* __restrict__ outB,
    int K, int lda, int ldb, int N)
{
  __shared__ __align__(16) bf16 SH[16384];     // As[2][4096] | Bs[2][4096]; reused as C-tile
  bf16 (*As)[4096] = (bf16(*)[4096])SH;
  bf16 (*Bs)[4096] = (bf16(*)[4096])(SH + 8192);
  const int tid = threadIdx.x;
  const int lane = tid & 63;
  const int wv = tid >> 6;
  const int wrM = wv >> 1, wcN = wv & 1;
  const int col16 = lane & 15, kgrp = lane >> 4;
  const int cpx = gridDim.x >> 3;
  const int bxs = ((int)blockIdx.x & 7) * cpx + ((int)blockIdx.x >> 3);
  const int m0 = bxs * 128;
  const int n0 = blockIdx.y * 128;

  const int srow = tid >> 2;
  const int cslot = tid & 3;
  const int cs = (cslot ^ ((srow >> 1) & 3)) * 8;   // source-side chunk swizzle
  const bf16 *ap0, *ap1;
  if constexpr (STG == 0){
    ap0 = A + (size_t)(m0 + srow) * lda;
    ap1 = ap0 + (size_t)64 * lda;
  } else {
    const bf16* t2[2];
    #pragma unroll
    for (int i = 0; i < 2; ++i){
      int p = m0 + srow + i * 64;
      int b = p >> 12, y = (p >> 6) & 63, xx = p & 63;
      t2[i] = A + (size_t)((b * 66 + y) * 66 + xx) * 384;
    }
    ap0 = t2[0]; ap1 = t2[1];
  }
  const bf16* bp0 = BT + (size_t)(n0 + srow) * ldb;
  const bf16* bp1 = bp0 + (size_t)64 * ldb;

  auto stage = [&](int bufi, size_t ao, size_t bo){
    gload16(ap0 + ao + cs, (char*)(&As[bufi][0]) + tid * 16);
    gload16(ap1 + ao + cs, (char*)(&As[bufi][0]) + 4096 + tid * 16);
    gload16(bp0 + bo + cs, (char*)(&Bs[bufi][0]) + tid * 16);
    gload16(bp1 + bo + cs, (char*)(&Bs[bufi][0]) + 4096 + tid * 16);
  };

  f32x4 acc[4][4];
  f32x4 z4 = {0.f,0.f,0.f,0.f};
  #pragma unroll
  for (int mi = 0; mi < 4; ++mi)
    #pragma unroll
    for (int ni = 0; ni < 4; ++ni) acc[mi][ni] = z4;

  const int rs = (kgrp ^ ((col16 >> 1) & 3)) * 8;   // read-side swizzled chunk

  const int nt = K >> 5;
  stage(0, 0, 0);
  __syncthreads();
  for (int s = 0; s < nt; ++s){
    const int cb = s & 1;
    if (s + 1 < nt){
      size_t ao, bo;
      if constexpr (STG == 2){
        int dy = (s + 1) / 36;
        int kp = ((s + 1) - dy * 36) << 5;
        ao = (size_t)dy * 25344 + kp;
        bo = (size_t)dy * 1152 + kp;
      } else {
        ao = (size_t)(s + 1) << 5;
        bo = ao;
      }
      stage(cb ^ 1, ao, bo);
    }
    s16x8 af[4], bfv[4];
    #pragma unroll
    for (int i = 0; i < 4; ++i)
      af[i] = *(const s16x8*)(&As[cb][(wrM * 64 + i * 16 + col16) * 32 + rs]);
    #pragma unroll
    for (int i = 0; i < 4; ++i)
      bfv[i] = *(const s16x8*)(&Bs[cb][(wcN * 64 + i * 16 + col16) * 32 + rs]);
    #pragma unroll
    for (int mi = 0; mi < 4; ++mi)
      #pragma unroll
      for (int ni = 0; ni < 4; ++ni)
        acc[mi][ni] = mfma16(af[mi], bfv[ni], acc[mi][ni]);
    __syncthreads();
  }

  // epilogue: stage C-tile into LDS (bank-swizzled), then coalesced copy-out
  #pragma unroll
  for (int mi = 0; mi < 4; ++mi){
    #pragma unroll
    for (int ni = 0; ni < 4; ++ni){
      #pragma unroll
      for (int e = 0; e < 4; ++e){
        int rl = wrM * 64 + mi * 16 + kgrp * 4 + e;
        int cl = wcN * 64 + ni * 16 + col16;
        float v = acc[mi][ni][e];
        float t;
        if constexpr (MODE == 2){
          t = geluf(v + bias[n0 + cl]);
        } else if constexpr (MODE == 4){
          t = v;
        } else {
          t = v + bias[n0 + cl];
        }
        SH[rl * 128 + (cl ^ (((rl >> 2) & 7) << 4))] = __float2bfloat16(t);
      }
    }
  }
  __syncthreads();
  #pragma unroll
  for (int p = 0; p < 8; ++p){
    int cid = p * 256 + tid;
    int r = cid >> 4, c = cid & 15;
    int swc = (c * 8) ^ (((r >> 2) & 7) << 4);
    s16x8 val = *(s16x8*)&SH[r * 128 + swc];
    size_t gbase = (size_t)(m0 + r) * N + n0 + c * 8;
    if constexpr (MODE == 1){
      f32x4 f0 = *(const f32x4*)(Af + gbase);
      f32x4 f1 = *(const f32x4*)(Af + gbase + 4);
      #pragma unroll
      for (int j = 0; j < 4; ++j){
        float a = __bfloat162float(__builtin_bit_cast(bf16, (unsigned short)val[j])) + f0[j];
        float b2 = __bfloat162float(__builtin_bit_cast(bf16, (unsigned short)val[j+4])) + f1[j];
        val[j]   = (short)__builtin_bit_cast(unsigned short, __float2bfloat16(a));
        val[j+4] = (short)__builtin_bit_cast(unsigned short, __float2bfloat16(b2));
      }
    } else if constexpr (MODE == 3){
      s16x8 rv = *(const s16x8*)(Rb + gbase);
      #pragma unroll
      for (int j = 0; j < 8; ++j){
        float a = __bfloat162float(__builtin_bit_cast(bf16, (unsigned short)val[j]))
                + __bfloat162float(__builtin_bit_cast(bf16, (unsigned short)rv[j]));
        val[j] = (short)__builtin_bit_cast(unsigned short, __float2bfloat16(a));
      }
    }
    *(s16x8*)(outB + gbase) = val;
  }
}

// ---------------- host ----------------
extern "C" void kernel_launch(void* const* d_in, const int* in_sizes, int n_in,
                              void* d_out, int out_size, void* d_ws, size_t ws_size,
                              hipStream_t stream) {
  (void)in_sizes; (void)n_in; (void)out_size;
  const float* x       = (const float*)d_in[0];
  const float* norm1_w = (const float*)d_in[1];
  const float* norm1_b = (const float*)d_in[2];
  const float* qkv_w   = (const float*)d_in[3];
  const float* qkv_b   = (const float*)d_in[4];
  const float* proj_w  = (const float*)d_in[5];
  const float* proj_b  = (const float*)d_in[6];
  const float* rph     = (const float*)d_in[7];
  const float* rpw     = (const float*)d_in[8];
  const float* norm2_w = (const float*)d_in[9];
  const float* norm2_b = (const float*)d_in[10];
  const float* fc1_w   = (const float*)d_in[11];
  const float* fc1_b   = (const float*)d_in[12];
  const float* fc2_w   = (const float*)d_in[13];
  const float* fc2_b   = (const float*)d_in[14];
  const float* conv1_w = (const float*)d_in[15];
  const float* ln1_w   = (const float*)d_in[16];
  const float* ln1_b   = (const float*)d_in[17];
  const float* conv2_w = (const float*)d_in[18];
  const float* ln2_w   = (const float*)d_in[19];
  const float* ln2_b   = (const float*)d_in[20];
  const float* conv3_w = (const float*)d_in[21];
  const float* ln3_w   = (const float*)d_in[22];
  const float* ln3_b   = (const float*)d_in[23];

  char* ws = (char*)d_ws;
  size_t off = 0;
  auto alloc = [&](size_t s){ size_t r = off; off = (off + s + 255) & ~(size_t)255; return r; };
  // persistent weights (~18 MB)
  bf16* wqkvT = (bf16*)(ws + alloc(2304UL * 768 * 2));
  bf16* wprojT = (bf16*)(ws + alloc(768UL * 768 * 2));
  bf16* wfc1T = (bf16*)(ws + alloc(3072UL * 768 * 2));
  bf16* wfc2T = (bf16*)(ws + alloc(768UL * 3072 * 2));
  bf16* wc1 = (bf16*)(ws + alloc(384UL * 768 * 2));
  bf16* wc2p = (bf16*)(ws + alloc(384UL * 3456 * 2));
  bf16* wc3 = (bf16*)(ws + alloc(768UL * 384 * 2));
  bf16* rphb = (bf16*)(ws + alloc(32UL * 64 * 2));
  bf16* rpwb = (bf16*)(ws + alloc(32UL * 64 * 2));
  bf16* oneh = (bf16*)(ws + alloc(224UL * 32 * 2));
  bf16* padkv = (bf16*)(ws + alloc(1536UL * 2));
  // R1 48MiB: qkvb chunk -> h1c -> b1p -> b2 -> x2cp
  char* R1 = ws + alloc(50331648UL);
  // R2 ~24.7MiB: relc -> ln2c -> c1 -> c2 -> c3h
  char* R2 = ws + alloc(25872384UL);
  size_t need = off;
  if (ws_size < need) return;

  bf16* qkvb   = (bf16*)R1;                       // [8192][2304]
  bf16* h1c    = (bf16*)R1;                       // [8192][3072]
  bf16* b1p    = (bf16*)R1;                       // [8][66][66][384] padded
  bf16* b2     = (bf16*)(R1 + 25165824UL);        // [32768][384]
  bf16* x2cp   = (bf16*)R1;                       // [16384][768]
  bf16* relc   = (bf16*)R2;                       // [600*196][32]
  bf16* ln2c   = (bf16*)R2;                       // [8192][768]
  bf16* c1     = (bf16*)R2;                       // [32768][384]
  bf16* c2     = (bf16*)R2;
  bf16* c3h    = (bf16*)R2;                       // [16384][768]
  bf16* ln1b   = (bf16*)d_out;
  bf16* attn_o = (bf16*)d_out;
  bf16* x2b    = (bf16*)d_out;
  bf16* x1b    = (bf16*)((char*)d_out + 50331648UL);
  float* xout  = (float*)d_out;

  dim3 blk(256);
  k_transpose_cast<<<dim3(72, 24), blk, 0, stream>>>(qkv_w, wqkvT, 768, 2304);
  k_transpose_cast<<<dim3(24, 24), blk, 0, stream>>>(proj_w, wprojT, 768, 768);
  k_transpose_cast<<<dim3(96, 24), blk, 0, stream>>>(fc1_w, wfc1T, 768, 3072);
  k_transpose_cast<<<dim3(24, 96), blk, 0, stream>>>(fc2_w, wfc2T, 3072, 768);
  k_cast<<<dim3(1152), blk, 0, stream>>>(conv1_w, wc1, 294912);
  k_cast<<<dim3(1152), blk, 0, stream>>>(conv3_w, wc3, 294912);
  k_permute_conv2<<<dim3(5184), blk, 0, stream>>>(conv2_w, wc2p);
  k_zero<<<dim3(1), blk, 0, stream>>>(rphb, 256);
  k_zero<<<dim3(1), blk, 0, stream>>>(rpwb, 256);
  k_cast<<<dim3(7), blk, 0, stream>>>(rph, rphb, 1728);
  k_cast<<<dim3(7), blk, 0, stream>>>(rpw, rpwb, 1728);
  k_onehot<<<dim3(1), blk, 0, stream>>>(oneh);
  k_padkv<<<dim3(6), blk, 0, stream>>>(qkv_b, padkv);
  k_zero<<<dim3(1838), blk, 0, stream>>>(relc, 470400);
  // LN1 into d_out[0:48MiB]
  k_lnrow<float><<<dim3(8192), blk, 0, stream>>>(x, norm1_w, norm1_b, ln1b);
  // attention: 4 chunks of 2 images (= 50 windows); qkv 256-tile GEMM, attn in-place over ln1b
  for (int c = 0; c < 4; ++c){
    k_gemm256<5><<<dim3(32, 9), dim3(512), 0, stream>>>(ln1b + (size_t)c * 8192 * 768, wqkvT, qkv_b,
                                                        qkvb, 768, 768, 768, 2304);
    k_relm<<<dim3(2100), blk, 0, stream>>>(qkvb, rphb, rpwb, relc);
    k_attn<<<dim3(600), blk, 0, stream>>>(qkvb, relc, oneh, padkv, attn_o, c * 50);
  }
  // proj + residual(x fp32) -> x1b bf16 (d_out[48:96])
  k_gemm<1,0><<<dim3(256, 6), blk, 0, stream>>>(attn_o, wprojT, proj_b, x, nullptr, x1b,
                                                768, 768, 768, 768);
  // MLP: 4 chunks of 8192 rows; fc1 on 256-tile; fc2 -> x2b bf16 (d_out[0:48])
  for (int c = 0; c < 4; ++c){
    size_t R = (size_t)c * 8192;
    k_lnrow<bf16><<<dim3(2048), blk, 0, stream>>>(x1b + R * 768, norm2_w, norm2_b, ln2c);
    k_gemm256<2><<<dim3(32, 12), dim3(512), 0, stream>>>(ln2c, wfc1T, fc1_b, h1c, 768, 768, 768, 3072);
    k_gemm<3,0><<<dim3(64, 6), blk, 0, stream>>>(h1c, wfc2T, fc2_b, nullptr, x1b + R * 768, x2b + R * 768,
                                                 3072, 3072, 3072, 768);
  }
  // conv1
  k_gemm<4,0><<<dim3(256, 3), blk, 0, stream>>>(x2b, wc1, nullptr, nullptr, nullptr, c1,
                                                768, 768, 768, 384);
  k_zero<<<dim3(6534), blk, 0, stream>>>(b1p, 1672704);
  k_lncf_gelu<bf16, true><<<dim3(8192), blk, 0, stream>>>(c1, ln1_w, ln1_b, b1p);
  // conv2
  k_gemm<4,2><<<dim3(256, 3), blk, 0, stream>>>(b1p, wc2p, nullptr, nullptr, nullptr, c2,
                                                3456, 0, 3456, 384);
  k_lncf_gelu<bf16, false><<<dim3(8192), blk, 0, stream>>>(c2, ln2_w, ln2_b, b2);
  // conv3 upper half + final
  k_gemm<4,0><<<dim3(128, 6), blk, 0, stream>>>(b2 + (size_t)16384 * 384, wc3, nullptr, nullptr, nullptr, c3h,
                                                384, 384, 384, 768);
  k_final<<<dim3(4096), blk, 0, stream>>>(c3h, ln3_w, ln3_b, x2b + (size_t)16384 * 768,
                                          xout + (size_t)16384 * 768, 16384);
  // conv3 lower half; stash x2b lower half; single final
  k_gemm<4,0><<<dim3(128, 6), blk, 0, stream>>>(b2, wc3, nullptr, nullptr, nullptr, c3h,
                                                384, 384, 384, 768);
  k_copy<<<dim3(6144), blk, 0, stream>>>(x2b, x2cp, 1572864);
  k_final<<<dim3(4096), blk, 0, stream>>>(c3h, ln3_w, ln3_b, x2cp, xout, 16384);
}

// Round 17
// 1480.487 us; speedup vs baseline: 1.1115x; 1.1115x over previous
//
#include <hip/hip_runtime.h>
#include <hip/hip_bf16.h>

typedef __attribute__((ext_vector_type(8))) short s16x8;
typedef __attribute__((ext_vector_type(4))) short s16x4;
typedef __attribute__((ext_vector_type(4))) float f32x4;
typedef __hip_bfloat16 bf16;

__device__ __forceinline__ f32x4 mfma16(s16x8 a, s16x8 b, f32x4 c){
  return __builtin_amdgcn_mfma_f32_16x16x32_bf16(a, b, c, 0, 0, 0);
}
__device__ __forceinline__ float geluf(float x){
  return 0.5f * x * (1.f + erff(x * 0.70710678118654752f));
}
__device__ __forceinline__ void gload16(const bf16* g, void* l){
  __builtin_amdgcn_global_load_lds(
      (const __attribute__((address_space(1))) unsigned int*)(g),
      (__attribute__((address_space(3))) unsigned int*)(l), 16, 0, 0);
}

// ---------------- weight prep ----------------
__global__ __launch_bounds__(256) void k_transpose_cast(const float* __restrict__ in,
                                                        bf16* __restrict__ out, int K, int N){
  __shared__ float t[32][33];
  int n0 = blockIdx.x * 32, k0 = blockIdx.y * 32;
  int tx = threadIdx.x & 31, ty = threadIdx.x >> 5;
  #pragma unroll
  for (int j = 0; j < 4; ++j) t[ty + j*8][tx] = in[(size_t)(k0 + ty + j*8) * N + n0 + tx];
  __syncthreads();
  #pragma unroll
  for (int j = 0; j < 4; ++j) out[(size_t)(n0 + ty + j*8) * K + k0 + tx] = __float2bfloat16(t[tx][ty + j*8]);
}

__global__ __launch_bounds__(256) void k_cast(const float* __restrict__ in, bf16* __restrict__ out, int n){
  int i = blockIdx.x * 256 + threadIdx.x;
  if (i < n) out[i] = __float2bfloat16(in[i]);
}

// conv2_w [384][384][3][3] -> [cout][dy][dx*384+ci]  (ldb = 3456)
__global__ __launch_bounds__(256) void k_permute_conv2(const float* __restrict__ in, bf16* __restrict__ out){
  int i = blockIdx.x * 256 + threadIdx.x;   // 1327104 total
  int co = i / 3456;
  int r = i - co * 3456;
  int dy = r / 1152;
  int r2 = r - dy * 1152;
  int dx = r2 / 384;
  int ci = r2 - dx * 384;
  out[i] = __float2bfloat16(in[(size_t)((co * 384 + ci) * 3 + dy) * 3 + dx]);
}

// zero-fill bf16 buffer, n8 = elements/8
__global__ __launch_bounds__(256) void k_zero(bf16* __restrict__ p, int n8){
  int i = blockIdx.x * 256 + threadIdx.x;
  if (i < n8){
    s16x8 z = {0,0,0,0,0,0,0,0};
    *(s16x8*)(p + (size_t)i * 8) = z;
  }
}

// bf16 copy, n8 = elements/8
__global__ __launch_bounds__(256) void k_copy(const bf16* __restrict__ in, bf16* __restrict__ out, int n8){
  int i = blockIdx.x * 256 + threadIdx.x;
  if (i < n8){
    s16x8 v = *(const s16x8*)(in + (size_t)i * 8);
    *(s16x8*)(out + (size_t)i * 8) = v;
  }
}

// onehot table: oneh[j][32], j in [0,224): oneh[j][j/14] = 1, oneh[j][16 + j%14] = 1 (j<196)
__global__ __launch_bounds__(256) void k_onehot(bf16* __restrict__ oneh){
  for (int idx = threadIdx.x; idx < 7168; idx += 256){
    int j = idx >> 5, kk = idx & 31;
    float v = 0.f;
    if (j < 196){
      if (kk == j / 14) v = 1.f;
      if (kk == 16 + (j - (j / 14) * 14)) v = 1.f;
    }
    oneh[idx] = __float2bfloat16(v);
  }
}

// pad K/V rows from qkv bias: padkv[0:768) = 0.125*qkv_b[768+i]; padkv[768:1536) = qkv_b[1536+i]
__global__ __launch_bounds__(256) void k_padkv(const float* __restrict__ qkv_b, bf16* __restrict__ padkv){
  int i = blockIdx.x * 256 + threadIdx.x;
  if (i < 1536){
    float v = (i < 768) ? qkv_b[768 + i] * 0.125f : qkv_b[1536 + (i - 768)];
    padkv[i] = __float2bfloat16(v);
  }
}

// ---------------- row LayerNorm (768 wide, eps 1e-5) -> bf16 ----------------
template<typename Tin>
__global__ __launch_bounds__(256) void k_lnrow(const Tin* __restrict__ xin, const float* __restrict__ w,
                                               const float* __restrict__ b, bf16* __restrict__ out){
  int row = blockIdx.x * 4 + (threadIdx.x >> 6);
  int lane = threadIdx.x & 63;
  const Tin* src = xin + (size_t)row * 768;
  bf16* dst = out + (size_t)row * 768;
  float v[12]; float s = 0.f, sq = 0.f;
  #pragma unroll
  for (int p = 0; p < 3; ++p){
    int c0 = lane * 4 + p * 256;
    if constexpr (sizeof(Tin) == 4){
      f32x4 t = *(const f32x4*)(src + c0);
      #pragma unroll
      for (int e = 0; e < 4; ++e) v[p*4+e] = t[e];
    } else {
      s16x4 t = *(const s16x4*)(src + c0);
      #pragma unroll
      for (int e = 0; e < 4; ++e) v[p*4+e] = __bfloat162float(__builtin_bit_cast(bf16, (unsigned short)t[e]));
    }
    #pragma unroll
    for (int e = 0; e < 4; ++e){ s += v[p*4+e]; sq += v[p*4+e] * v[p*4+e]; }
  }
  #pragma unroll
  for (int o = 1; o < 64; o <<= 1){ s += __shfl_xor(s, o); sq += __shfl_xor(sq, o); }
  float mean = s * (1.f / 768.f);
  float rstd = rsqrtf(sq * (1.f / 768.f) - mean * mean + 1e-5f);
  #pragma unroll
  for (int p = 0; p < 3; ++p){
    int c0 = lane * 4 + p * 256;
    s16x4 o4;
    #pragma unroll
    for (int e = 0; e < 4; ++e){
      bf16 h = __float2bfloat16((v[p*4+e] - mean) * rstd * w[c0 + e] + b[c0 + e]);
      o4[e] = (short)__builtin_bit_cast(unsigned short, h);
    }
    *(s16x4*)(dst + c0) = o4;
  }
}

// channel-first LN (eps 1e-6) + GELU over C=384; PAD: write into [8][66][66][384] interior
template<typename Tin, bool PAD>
__global__ __launch_bounds__(256) void k_lncf_gelu(const Tin* __restrict__ in, const float* __restrict__ w,
                                                   const float* __restrict__ b, bf16* __restrict__ out){
  int row = blockIdx.x * 4 + (threadIdx.x >> 6);
  int lane = threadIdx.x & 63;
  const Tin* src = in + (size_t)row * 384;
  bf16* dst;
  if constexpr (PAD){
    int bb = row >> 12, y = (row >> 6) & 63, xx = row & 63;
    dst = out + (size_t)((bb * 66 + y + 1) * 66 + (xx + 1)) * 384;
  } else {
    dst = out + (size_t)row * 384;
  }
  float buf[6]; float s = 0.f, sq = 0.f;
  #pragma unroll
  for (int p = 0; p < 6; ++p){
    float v;
    if constexpr (sizeof(Tin) == 4) v = src[lane + p * 64];
    else v = __bfloat162float(src[lane + p * 64]);
    buf[p] = v; s += v; sq += v * v;
  }
  #pragma unroll
  for (int o = 1; o < 64; o <<= 1){ s += __shfl_xor(s, o); sq += __shfl_xor(sq, o); }
  float mean = s * (1.f / 384.f);
  float rstd = rsqrtf(sq * (1.f / 384.f) - mean * mean + 1e-6f);
  #pragma unroll
  for (int p = 0; p < 6; ++p){
    int c = lane + p * 64;
    dst[c] = __float2bfloat16(geluf((buf[p] - mean) * rstd * w[c] + b[c]));
  }
}

// final: outp[row] = fp32(res[row]) + LN_cf(c3[row]); nrows rows
__global__ __launch_bounds__(256) void k_final(const bf16* __restrict__ c3, const float* __restrict__ w,
                                               const float* __restrict__ b, const bf16* __restrict__ res,
                                               float* __restrict__ outp, int nrows){
  int row = blockIdx.x * 4 + (threadIdx.x >> 6);
  if (row >= nrows) return;
  int lane = threadIdx.x & 63;
  const bf16* src = c3 + (size_t)row * 768;
  const bf16* rsp = res + (size_t)row * 768;
  float* dst = outp + (size_t)row * 768;
  float buf[12]; float s = 0.f, sq = 0.f;
  #pragma unroll
  for (int p = 0; p < 12; ++p){
    float v = __bfloat162float(src[lane + p * 64]);
    buf[p] = v; s += v; sq += v * v;
  }
  #pragma unroll
  for (int o = 1; o < 64; o <<= 1){ s += __shfl_xor(s, o); sq += __shfl_xor(sq, o); }
  float mean = s * (1.f / 768.f);
  float rstd = rsqrtf(sq * (1.f / 768.f) - mean * mean + 1e-6f);
  #pragma unroll
  for (int p = 0; p < 12; ++p){
    int c = lane + p * 64;
    dst[c] = __bfloat162float(rsp[c]) + (buf[p] - mean) * rstd * w[c] + b[c];
  }
}

// ---------------- rel-pos tables via MFMA (Q from token-major qkvb chunk) ----------------
__global__ __launch_bounds__(256) void k_relm(const bf16* __restrict__ qkvb, const bf16* __restrict__ rphb,
                                              const bf16* __restrict__ rpwb, bf16* __restrict__ relc){
  const int lane = threadIdx.x & 63, wv = threadIdx.x >> 6;
  const int col16 = lane & 15, kgrp = lane >> 4;
  const int w = blockIdx.x * 4 + wv;            // 8400 waves per chunk
  const int wh = w / 14, r = w - (w / 14) * 14; // wh 0..599 chunk-local
  const int wdwL = wh / 12, hd = wh - wdwL * 12;
  const int bloc = wdwL / 25;
  const int wrm = wdwL - bloc * 25;
  const int wy = wrm / 5, wx = wrm - (wrm / 5) * 5;
  const int qrow = r * 14 + col16;
  const int qq = qrow > 195 ? 195 : qrow;
  int qy = wy * 14 + qq / 14, qx = wx * 14 + qq - (qq / 14) * 14;
  if (qy > 63) qy = 63;
  if (qx > 63) qx = 63;
  const bf16* qa = qkvb + (size_t)(bloc * 4096 + qy * 64 + qx) * 2304 + hd * 64 + kgrp * 8;
  s16x8 a0 = *(const s16x8*)qa;
  s16x8 a1 = *(const s16x8*)(qa + 32);
  #pragma unroll
  for (int t = 0; t < 2; ++t){
    const bf16* bh = rphb + (t * 16 + col16) * 64 + kgrp * 8;
    const bf16* bw = rpwb + (t * 16 + col16) * 64 + kgrp * 8;
    f32x4 zh = {0.f,0.f,0.f,0.f}, zw = zh;
    zh = mfma16(a0, *(const s16x8*)bh, zh);
    zh = mfma16(a1, *(const s16x8*)(bh + 32), zh);
    zw = mfma16(a0, *(const s16x8*)bw, zw);
    zw = mfma16(a1, *(const s16x8*)(bw + 32), zw);
    #pragma unroll
    for (int e = 0; e < 4; ++e){
      int m = kgrp * 4 + e;
      if (m < 14){
        int q = r * 14 + m;
        int j = t * 16 + col16;
        size_t base = ((size_t)wh * 196 + q) * 32;
        int kk = r + 13 - j;
        if (kk >= 0 && kk <= 13) relc[base + kk] = __float2bfloat16(zh[e]);
        int kkw = m + 13 - j;
        if (kkw >= 0 && kkw <= 13) relc[base + 16 + kkw] = __float2bfloat16(zw[e]);
      }
    }
  }
}

// ---------------- attention (chunk of 50 windows x 12 heads = 600 blocks) ----------------
__global__ __launch_bounds__(256) void k_attn(const bf16* __restrict__ qkvb,
                                              const bf16* __restrict__ relc,
                                              const bf16* __restrict__ oneh,
                                              const bf16* __restrict__ padkv,
                                              bf16* __restrict__ out, int wdw_base){
  __shared__ __align__(16) bf16 Vt[64][236];
  __shared__ __align__(16) bf16 Pst[4][16][236];
  const int tid = threadIdx.x;
  const int lane = tid & 63, wv = tid >> 6;
  const int col16 = lane & 15, kgrp = lane >> 4;
  const int bxl = blockIdx.x;
  const int wdwL = bxl / 12, hd = bxl - wdwL * 12;
  const int wdw = wdw_base + wdwL;
  const int bb = wdw / 25, wr = wdw - bb * 25;
  const int wy = wr / 5, wx = wr - (wr / 5) * 5;
  const int bloc = wdwL / 25;
  const bf16* rc = relc + (size_t)bxl * 196 * 32;
  const bf16* padK = padkv;
  const bf16* padV = padkv + 768;

  for (int i = tid; i < 3584; i += 256){
    int tok = i >> 4;
    int d0 = (i & 15) * 4;
    if (tok < 196){
      int y = wy * 14 + tok / 14, xx = wx * 14 + tok - (tok / 14) * 14;
      const bf16* src;
      if (y < 64 && xx < 64)
        src = qkvb + (size_t)(bloc * 4096 + y * 64 + xx) * 2304 + 1536 + hd * 64 + d0;
      else
        src = padV + hd * 64 + d0;
      s16x4 vv = *(const s16x4*)src;
      Vt[d0][tok]   = __builtin_bit_cast(bf16, (unsigned short)vv[0]);
      Vt[d0+1][tok] = __builtin_bit_cast(bf16, (unsigned short)vv[1]);
      Vt[d0+2][tok] = __builtin_bit_cast(bf16, (unsigned short)vv[2]);
      Vt[d0+3][tok] = __builtin_bit_cast(bf16, (unsigned short)vv[3]);
    } else {
      bf16 z = __float2bfloat16(0.f);
      Vt[d0][tok] = z; Vt[d0+1][tok] = z; Vt[d0+2][tok] = z; Vt[d0+3][tok] = z;
    }
  }
  __syncthreads();

  for (int band = wv; band < 14; band += 4){
    const int qrow = band * 16 + col16;
    const int qq = qrow < 196 ? qrow : 195;
    int qy = wy * 14 + qq / 14, qx = wx * 14 + qq - (qq / 14) * 14;
    if (qy > 63) qy = 63;
    if (qx > 63) qx = 63;
    const bf16* qa = qkvb + (size_t)(bloc * 4096 + qy * 64 + qx) * 2304 + hd * 64 + kgrp * 8;
    s16x8 a0 = *(const s16x8*)(qa);
    s16x8 a1 = *(const s16x8*)(qa + 32);
    s16x8 a2 = *(const s16x8*)(rc + (size_t)qq * 32 + kgrp * 8);
    f32x4 s[14];
    #pragma unroll
    for (int t = 0; t < 14; ++t){
      int j = t * 16 + col16;
      int jc = j < 196 ? j : 195;
      int ky = wy * 14 + jc / 14, kx = wx * 14 + jc - (jc / 14) * 14;
      const bf16* kb;
      if (ky < 64 && kx < 64)
        kb = qkvb + (size_t)(bloc * 4096 + ky * 64 + kx) * 2304 + 768 + hd * 64 + kgrp * 8;
      else
        kb = padK + hd * 64 + kgrp * 8;
      s16x8 oh = *(const s16x8*)(oneh + (size_t)j * 32 + kgrp * 8);
      f32x4 z = {0.f, 0.f, 0.f, 0.f};
      z = mfma16(a0, *(const s16x8*)kb, z);
      z = mfma16(a1, *(const s16x8*)(kb + 32), z);
      z = mfma16(a2, oh, z);
      s[t] = z;
    }
    float mx[4] = {-1e30f, -1e30f, -1e30f, -1e30f};
    #pragma unroll
    for (int t = 0; t < 14; ++t){
      bool valid = (t * 16 + col16) < 196;
      #pragma unroll
      for (int r = 0; r < 4; ++r){
        float v = valid ? s[t][r] : -1e30f;
        s[t][r] = v;
        mx[r] = fmaxf(mx[r], v);
      }
    }
    #pragma unroll
    for (int r = 0; r < 4; ++r)
      #pragma unroll
      for (int o = 1; o < 16; o <<= 1) mx[r] = fmaxf(mx[r], __shfl_xor(mx[r], o));
    float sm[4] = {0.f, 0.f, 0.f, 0.f};
    #pragma unroll
    for (int t = 0; t < 14; ++t)
      #pragma unroll
      for (int r = 0; r < 4; ++r){
        float p = __expf(s[t][r] - mx[r]);
        s[t][r] = p; sm[r] += p;
      }
    #pragma unroll
    for (int r = 0; r < 4; ++r){
      #pragma unroll
      for (int o = 1; o < 16; o <<= 1) sm[r] += __shfl_xor(sm[r], o);
      sm[r] = 1.f / sm[r];
    }
    #pragma unroll
    for (int t = 0; t < 14; ++t)
      #pragma unroll
      for (int r = 0; r < 4; ++r)
        Pst[wv][kgrp * 4 + r][t * 16 + col16] = __float2bfloat16(s[t][r] * sm[r]);
    f32x4 o0 = {0.f,0.f,0.f,0.f}, o1 = o0, o2 = o0, o3 = o0;
    #pragma unroll
    for (int ks = 0; ks < 7; ++ks){
      s16x8 pa = *(const s16x8*)&Pst[wv][col16][ks * 32 + kgrp * 8];
      s16x8 v0 = *(const s16x8*)&Vt[col16][ks * 32 + kgrp * 8];
      s16x8 v1 = *(const s16x8*)&Vt[16 + col16][ks * 32 + kgrp * 8];
      s16x8 v2 = *(const s16x8*)&Vt[32 + col16][ks * 32 + kgrp * 8];
      s16x8 v3 = *(const s16x8*)&Vt[48 + col16][ks * 32 + kgrp * 8];
      o0 = mfma16(pa, v0, o0); o1 = mfma16(pa, v1, o1);
      o2 = mfma16(pa, v2, o2); o3 = mfma16(pa, v3, o3);
    }
    f32x4 oo[4] = {o0, o1, o2, o3};
    #pragma unroll
    for (int nt = 0; nt < 4; ++nt)
      #pragma unroll
      for (int r = 0; r < 4; ++r){
        int q = band * 16 + kgrp * 4 + r;
        if (q < 196){
          int y = wy * 14 + q / 14, xx = wx * 14 + (q - (q / 14) * 14);
          if (y < 64 && xx < 64){
            size_t tokidx = (size_t)((bb * 64 + y) * 64 + xx);
            out[tokidx * 768 + hd * 64 + nt * 16 + col16] = __float2bfloat16(oo[nt][r]);
          }
        }
      }
  }
}

// ---------------- LDS-staged MFMA GEMM (128x128, 4 waves, chunk-XOR swizzle, XCD swizzle) ----------------
// Coalesced epilogue via LDS C-tile restage; residual added at copy-out.
// MODE 1: + bias + Af(fp32)   MODE 2: gelu(+bias)   MODE 3: + bias + Rb(bf16)
// MODE 4: plain               MODE 5: qkv (+bias, 0.125 on K cols)
// STG 0: linear rows  STG 2: conv2 padded dy-shift
template<int MODE, int STG>
__global__ __launch_bounds__(256) void k_gemm(
    const bf16* __restrict__ A, const bf16* __restrict__ BT,
    const float* __restrict__ bias, const float* __restrict__ Af,
    const bf16* __restrict__ Rb, bf16* __restrict__ outB,
    int K, int lda, int ldb, int N)
{
  __shared__ __align__(16) bf16 SH[16384];     // As[2][4096] | Bs[2][4096]; reused as C-tile
  bf16 (*As)[4096] = (bf16(*)[4096])SH;
  bf16 (*Bs)[4096] = (bf16(*)[4096])(SH + 8192);
  const int tid = threadIdx.x;
  const int lane = tid & 63;
  const int wv = tid >> 6;
  const int wrM = wv >> 1, wcN = wv & 1;
  const int col16 = lane & 15, kgrp = lane >> 4;
  const int cpx = gridDim.x >> 3;
  const int bxs = ((int)blockIdx.x & 7) * cpx + ((int)blockIdx.x >> 3);
  const int m0 = bxs * 128;
  const int n0 = blockIdx.y * 128;

  const int srow = tid >> 2;
  const int cslot = tid & 3;
  const int cs = (cslot ^ ((srow >> 1) & 3)) * 8;   // source-side chunk swizzle
  const bf16 *ap0, *ap1;
  if constexpr (STG == 0){
    ap0 = A + (size_t)(m0 + srow) * lda;
    ap1 = ap0 + (size_t)64 * lda;
  } else {
    const bf16* t2[2];
    #pragma unroll
    for (int i = 0; i < 2; ++i){
      int p = m0 + srow + i * 64;
      int b = p >> 12, y = (p >> 6) & 63, xx = p & 63;
      t2[i] = A + (size_t)((b * 66 + y) * 66 + xx) * 384;
    }
    ap0 = t2[0]; ap1 = t2[1];
  }
  const bf16* bp0 = BT + (size_t)(n0 + srow) * ldb;
  const bf16* bp1 = bp0 + (size_t)64 * ldb;

  auto stage = [&](int bufi, size_t ao, size_t bo){
    gload16(ap0 + ao + cs, (char*)(&As[bufi][0]) + tid * 16);
    gload16(ap1 + ao + cs, (char*)(&As[bufi][0]) + 4096 + tid * 16);
    gload16(bp0 + bo + cs, (char*)(&Bs[bufi][0]) + tid * 16);
    gload16(bp1 + bo + cs, (char*)(&Bs[bufi][0]) + 4096 + tid * 16);
  };

  f32x4 acc[4][4];
  f32x4 z4 = {0.f,0.f,0.f,0.f};
  #pragma unroll
  for (int mi = 0; mi < 4; ++mi)
    #pragma unroll
    for (int ni = 0; ni < 4; ++ni) acc[mi][ni] = z4;

  const int rs = (kgrp ^ ((col16 >> 1) & 3)) * 8;   // read-side swizzled chunk

  const int nt = K >> 5;
  stage(0, 0, 0);
  __syncthreads();
  for (int s = 0; s < nt; ++s){
    const int cb = s & 1;
    if (s + 1 < nt){
      size_t ao, bo;
      if constexpr (STG == 2){
        int dy = (s + 1) / 36;
        int kp = ((s + 1) - dy * 36) << 5;
        ao = (size_t)dy * 25344 + kp;
        bo = (size_t)dy * 1152 + kp;
      } else {
        ao = (size_t)(s + 1) << 5;
        bo = ao;
      }
      stage(cb ^ 1, ao, bo);
    }
    s16x8 af[4], bfv[4];
    #pragma unroll
    for (int i = 0; i < 4; ++i)
      af[i] = *(const s16x8*)(&As[cb][(wrM * 64 + i * 16 + col16) * 32 + rs]);
    #pragma unroll
    for (int i = 0; i < 4; ++i)
      bfv[i] = *(const s16x8*)(&Bs[cb][(wcN * 64 + i * 16 + col16) * 32 + rs]);
    #pragma unroll
    for (int mi = 0; mi < 4; ++mi)
      #pragma unroll
      for (int ni = 0; ni < 4; ++ni)
        acc[mi][ni] = mfma16(af[mi], bfv[ni], acc[mi][ni]);
    __syncthreads();
  }

  // epilogue: stage C-tile into LDS (bank-swizzled), then coalesced copy-out
  #pragma unroll
  for (int mi = 0; mi < 4; ++mi){
    #pragma unroll
    for (int ni = 0; ni < 4; ++ni){
      #pragma unroll
      for (int e = 0; e < 4; ++e){
        int rl = wrM * 64 + mi * 16 + kgrp * 4 + e;
        int cl = wcN * 64 + ni * 16 + col16;
        float v = acc[mi][ni][e];
        float t;
        if constexpr (MODE == 2){
          t = geluf(v + bias[n0 + cl]);
        } else if constexpr (MODE == 5){
          int col = n0 + cl;
          t = (v + bias[col]) * ((col >= 768 && col < 1536) ? 0.125f : 1.f);
        } else if constexpr (MODE == 4){
          t = v;
        } else {
          t = v + bias[n0 + cl];
        }
        SH[rl * 128 + (cl ^ (((rl >> 2) & 7) << 4))] = __float2bfloat16(t);
      }
    }
  }
  __syncthreads();
  #pragma unroll
  for (int p = 0; p < 8; ++p){
    int cid = p * 256 + tid;
    int r = cid >> 4, c = cid & 15;
    int swc = (c * 8) ^ (((r >> 2) & 7) << 4);
    s16x8 val = *(s16x8*)&SH[r * 128 + swc];
    size_t gbase = (size_t)(m0 + r) * N + n0 + c * 8;
    if constexpr (MODE == 1){
      f32x4 f0 = *(const f32x4*)(Af + gbase);
      f32x4 f1 = *(const f32x4*)(Af + gbase + 4);
      #pragma unroll
      for (int j = 0; j < 4; ++j){
        float a = __bfloat162float(__builtin_bit_cast(bf16, (unsigned short)val[j])) + f0[j];
        float b2 = __bfloat162float(__builtin_bit_cast(bf16, (unsigned short)val[j+4])) + f1[j];
        val[j]   = (short)__builtin_bit_cast(unsigned short, __float2bfloat16(a));
        val[j+4] = (short)__builtin_bit_cast(unsigned short, __float2bfloat16(b2));
      }
    } else if constexpr (MODE == 3){
      s16x8 rv = *(const s16x8*)(Rb + gbase);
      #pragma unroll
      for (int j = 0; j < 8; ++j){
        float a = __bfloat162float(__builtin_bit_cast(bf16, (unsigned short)val[j]))
                + __bfloat162float(__builtin_bit_cast(bf16, (unsigned short)rv[j]));
        val[j] = (short)__builtin_bit_cast(unsigned short, __float2bfloat16(a));
      }
    }
    *(s16x8*)(outB + gbase) = val;
  }
}

// ---------------- host ----------------
extern "C" void kernel_launch(void* const* d_in, const int* in_sizes, int n_in,
                              void* d_out, int out_size, void* d_ws, size_t ws_size,
                              hipStream_t stream) {
  (void)in_sizes; (void)n_in; (void)out_size;
  const float* x       = (const float*)d_in[0];
  const float* norm1_w = (const float*)d_in[1];
  const float* norm1_b = (const float*)d_in[2];
  const float* qkv_w   = (const float*)d_in[3];
  const float* qkv_b   = (const float*)d_in[4];
  const float* proj_w  = (const float*)d_in[5];
  const float* proj_b  = (const float*)d_in[6];
  const float* rph     = (const float*)d_in[7];
  const float* rpw     = (const float*)d_in[8];
  const float* norm2_w = (const float*)d_in[9];
  const float* norm2_b = (const float*)d_in[10];
  const float* fc1_w   = (const float*)d_in[11];
  const float* fc1_b   = (const float*)d_in[12];
  const float* fc2_w   = (const float*)d_in[13];
  const float* fc2_b   = (const float*)d_in[14];
  const float* conv1_w = (const float*)d_in[15];
  const float* ln1_w   = (const float*)d_in[16];
  const float* ln1_b   = (const float*)d_in[17];
  const float* conv2_w = (const float*)d_in[18];
  const float* ln2_w   = (const float*)d_in[19];
  const float* ln2_b   = (const float*)d_in[20];
  const float* conv3_w = (const float*)d_in[21];
  const float* ln3_w   = (const float*)d_in[22];
  const float* ln3_b   = (const float*)d_in[23];

  char* ws = (char*)d_ws;
  size_t off = 0;
  auto alloc = [&](size_t s){ size_t r = off; off = (off + s + 255) & ~(size_t)255; return r; };
  // persistent weights (~18 MB)
  bf16* wqkvT = (bf16*)(ws + alloc(2304UL * 768 * 2));
  bf16* wprojT = (bf16*)(ws + alloc(768UL * 768 * 2));
  bf16* wfc1T = (bf16*)(ws + alloc(3072UL * 768 * 2));
  bf16* wfc2T = (bf16*)(ws + alloc(768UL * 3072 * 2));
  bf16* wc1 = (bf16*)(ws + alloc(384UL * 768 * 2));
  bf16* wc2p = (bf16*)(ws + alloc(384UL * 3456 * 2));
  bf16* wc3 = (bf16*)(ws + alloc(768UL * 384 * 2));
  bf16* rphb = (bf16*)(ws + alloc(32UL * 64 * 2));
  bf16* rpwb = (bf16*)(ws + alloc(32UL * 64 * 2));
  bf16* oneh = (bf16*)(ws + alloc(224UL * 32 * 2));
  bf16* padkv = (bf16*)(ws + alloc(1536UL * 2));
  // R1 48MiB: qkvb chunk -> h1c -> b1p -> b2 -> x2cp
  char* R1 = ws + alloc(50331648UL);
  // R2 ~24.7MiB: relc -> ln2c -> c1 -> c2 -> c3h
  char* R2 = ws + alloc(25872384UL);
  size_t need = off;
  if (ws_size < need) return;

  bf16* qkvb   = (bf16*)R1;                       // [8192][2304]
  bf16* h1c    = (bf16*)R1;                       // [8192][3072]
  bf16* b1p    = (bf16*)R1;                       // [8][66][66][384] padded
  bf16* b2     = (bf16*)(R1 + 25165824UL);        // [32768][384]
  bf16* x2cp   = (bf16*)R1;                       // [16384][768]
  bf16* relc   = (bf16*)R2;                       // [600*196][32]
  bf16* ln2c   = (bf16*)R2;                       // [8192][768]
  bf16* c1     = (bf16*)R2;                       // [32768][384]
  bf16* c2     = (bf16*)R2;
  bf16* c3h    = (bf16*)R2;                       // [16384][768]
  bf16* ln1b   = (bf16*)d_out;
  bf16* attn_o = (bf16*)d_out;
  bf16* x2b    = (bf16*)d_out;
  bf16* x1b    = (bf16*)((char*)d_out + 50331648UL);
  float* xout  = (float*)d_out;

  dim3 blk(256);
  k_transpose_cast<<<dim3(72, 24), blk, 0, stream>>>(qkv_w, wqkvT, 768, 2304);
  k_transpose_cast<<<dim3(24, 24), blk, 0, stream>>>(proj_w, wprojT, 768, 768);
  k_transpose_cast<<<dim3(96, 24), blk, 0, stream>>>(fc1_w, wfc1T, 768, 3072);
  k_transpose_cast<<<dim3(24, 96), blk, 0, stream>>>(fc2_w, wfc2T, 3072, 768);
  k_cast<<<dim3(1152), blk, 0, stream>>>(conv1_w, wc1, 294912);
  k_cast<<<dim3(1152), blk, 0, stream>>>(conv3_w, wc3, 294912);
  k_permute_conv2<<<dim3(5184), blk, 0, stream>>>(conv2_w, wc2p);
  k_zero<<<dim3(1), blk, 0, stream>>>(rphb, 256);
  k_zero<<<dim3(1), blk, 0, stream>>>(rpwb, 256);
  k_cast<<<dim3(7), blk, 0, stream>>>(rph, rphb, 1728);
  k_cast<<<dim3(7), blk, 0, stream>>>(rpw, rpwb, 1728);
  k_onehot<<<dim3(1), blk, 0, stream>>>(oneh);
  k_padkv<<<dim3(6), blk, 0, stream>>>(qkv_b, padkv);
  k_zero<<<dim3(1838), blk, 0, stream>>>(relc, 470400);
  // LN1 into d_out[0:48MiB]
  k_lnrow<float><<<dim3(8192), blk, 0, stream>>>(x, norm1_w, norm1_b, ln1b);
  // attention: 4 chunks of 2 images (= 50 windows); qkv token-major, attn in-place over ln1b
  for (int c = 0; c < 4; ++c){
    k_gemm<5,0><<<dim3(64, 18), blk, 0, stream>>>(ln1b + (size_t)c * 8192 * 768, wqkvT, qkv_b,
                                                  nullptr, nullptr, qkvb, 768, 768, 768, 2304);
    k_relm<<<dim3(2100), blk, 0, stream>>>(qkvb, rphb, rpwb, relc);
    k_attn<<<dim3(600), blk, 0, stream>>>(qkvb, relc, oneh, padkv, attn_o, c * 50);
  }
  // proj + residual(x fp32) -> x1b bf16 (d_out[48:96])
  k_gemm<1,0><<<dim3(256, 6), blk, 0, stream>>>(attn_o, wprojT, proj_b, x, nullptr, x1b,
                                                768, 768, 768, 768);
  // MLP: 4 chunks of 8192 rows; h1c in R1, ln2c in R2; fc2 -> x2b bf16 (d_out[0:48])
  for (int c = 0; c < 4; ++c){
    size_t R = (size_t)c * 8192;
    k_lnrow<bf16><<<dim3(2048), blk, 0, stream>>>(x1b + R * 768, norm2_w, norm2_b, ln2c);
    k_gemm<2,0><<<dim3(64, 24), blk, 0, stream>>>(ln2c, wfc1T, fc1_b, nullptr, nullptr, h1c,
                                                  768, 768, 768, 3072);
    k_gemm<3,0><<<dim3(64, 6), blk, 0, stream>>>(h1c, wfc2T, fc2_b, nullptr, x1b + R * 768, x2b + R * 768,
                                                 3072, 3072, 3072, 768);
  }
  // conv1
  k_gemm<4,0><<<dim3(256, 3), blk, 0, stream>>>(x2b, wc1, nullptr, nullptr, nullptr, c1,
                                                768, 768, 768, 384);
  k_zero<<<dim3(6534), blk, 0, stream>>>(b1p, 1672704);
  k_lncf_gelu<bf16, true><<<dim3(8192), blk, 0, stream>>>(c1, ln1_w, ln1_b, b1p);
  // conv2: 3 dy-shifted K=1152 passes accumulated in-kernel
  k_gemm<4,2><<<dim3(256, 3), blk, 0, stream>>>(b1p, wc2p, nullptr, nullptr, nullptr, c2,
                                                3456, 0, 3456, 384);
  k_lncf_gelu<bf16, false><<<dim3(8192), blk, 0, stream>>>(c2, ln2_w, ln2_b, b2);
  // conv3 upper half + final
  k_gemm<4,0><<<dim3(128, 6), blk, 0, stream>>>(b2 + (size_t)16384 * 384, wc3, nullptr, nullptr, nullptr, c3h,
                                                384, 384, 384, 768);
  k_final<<<dim3(4096), blk, 0, stream>>>(c3h, ln3_w, ln3_b, x2b + (size_t)16384 * 768,
                                          xout + (size_t)16384 * 768, 16384);
  // conv3 lower half; stash x2b lower half; single final
  k_gemm<4,0><<<dim3(128, 6), blk, 0, stream>>>(b2, wc3, nullptr, nullptr, nullptr, c3h,
                                                384, 384, 384, 768);
  k_copy<<<dim3(6144), blk, 0, stream>>>(x2b, x2cp, 1572864);
  k_final<<<dim3(4096), blk, 0, stream>>>(c3h, ln3_w, ln3_b, x2cp, xout, 16384);
}